// Round 3
// baseline (428.036 us; speedup 1.0000x reference)
//
#include <hip/hip_runtime.h>
#include <hip/hip_bf16.h>

#define DEV __device__ __forceinline__

typedef __attribute__((ext_vector_type(8))) short short8;
typedef __attribute__((ext_vector_type(4))) float f32x4;
typedef __bf16 bf16x8 __attribute__((ext_vector_type(8)));

DEV f32x4 mfma16(short8 a, short8 b, f32x4 c) {
    return __builtin_amdgcn_mfma_f32_16x16x32_bf16(
        __builtin_bit_cast(bf16x8, a), __builtin_bit_cast(bf16x8, b), c, 0, 0, 0);
}

DEV short f2bf(float x) {
    unsigned int u = __float_as_uint(x);
    u += 0x7fffu + ((u >> 16) & 1u);   // RNE
    return (short)(u >> 16);
}
DEV float sigmoidf_(float x) {
    x = fminf(15.f, fmaxf(-15.f, x));
    float e = __expf(-x);
    return __builtin_amdgcn_rcpf(1.f + e);
}
DEV float tanhf_(float x) {
    x = fminf(15.f, fmaxf(-15.f, x));
    float e = __expf(-2.f * x);
    float r = __builtin_amdgcn_rcpf(1.f + e);
    return fmaf(-2.f * e, r, 1.f);
}
DEV short8 pack8(float4 lo, float4 hi) {
    short8 r;
    r[0] = f2bf(lo.x); r[1] = f2bf(lo.y); r[2] = f2bf(lo.z); r[3] = f2bf(lo.w);
    r[4] = f2bf(hi.x); r[5] = f2bf(hi.y); r[6] = f2bf(hi.z); r[7] = f2bf(hi.w);
    return r;
}

// ---------------------------------------------------------------------------
// Fully fused stochastic 2-layer LSTM. 256 WGs x 16 batch rows, 4 waves.
// Inputs f32, OUTPUTS f32 (reference dtype is jnp.float32 -> d_out is float*).
// Compute in bf16 MFMA / f32 accumulate (bf16-tolerant threshold).
// rnn1out kept in LDS (61 level slots x 16 rows x 72-stride bf16).
// Phase-1 K layout (160, 5 tiles of 32): k0..63 = mem (Wx1 rows 4..67),
// 64..67 = x_main (Wx1 rows 0..3), 68..95 = zero, 96..159 = h (Wh1).
// Phase-2 K layout (128, 4 tiles): k0..63 = rnn1out (Wx2), 64..127 = h (Wh2).
// out = latent@W_out folded into h2 @ (W_lat@W_out).
// ---------------------------------------------------------------------------
__global__ __launch_bounds__(256, 1)
void k_fused(const float* __restrict__ xmain, const float* __restrict__ aux,
             const float* __restrict__ mem,   const float* __restrict__ eps1,
             const float* __restrict__ eps2,  const float* __restrict__ epsS,
             const float* __restrict__ Wsfc,  const float* __restrict__ bsfc,
             const float* __restrict__ Wsfc2, const float* __restrict__ bsfc2,
             const float* __restrict__ Wtoa,  const float* __restrict__ btoa,
             const float* __restrict__ Wtoa2, const float* __restrict__ btoa2,
             const float* __restrict__ Wx1,   const float* __restrict__ Wh1,
             const float* __restrict__ Wxs1,  const float* __restrict__ Whs1,
             const float* __restrict__ Wx2,   const float* __restrict__ Wh2,
             const float* __restrict__ Wxs2,  const float* __restrict__ Whs2,
             const float* __restrict__ Wlat,  const float* __restrict__ blat,
             const float* __restrict__ Wout,  const float* __restrict__ bout,
             const float* __restrict__ Wsfco, const float* __restrict__ bsfco,
             const float* __restrict__ Wmu,   const float* __restrict__ bmu,
             const float* __restrict__ Wlv,   const float* __restrict__ blv,
             float* __restrict__ outp, float* __restrict__ sfcp, float* __restrict__ memp)
{
    const int tid  = threadIdx.x;
    const int w    = tid >> 6;
    const int lane = tid & 63;
    const int q    = lane >> 4;
    const int n    = lane & 15;
    const int b0   = blockIdx.x << 4;
    const int col  = w * 16 + n;          // hidden column owned by this lane

    // LDS: 61 level slots (slot 60 = h0) of 16 rows x 72-stride bf16.
    __shared__ __align__(16) short r1[61 * 1152];      // 140544 B
    __shared__ __align__(16) short hbuf[2 * 1152];     //   4608 B
    __shared__ float comb_f[64 * 4];
    __shared__ float bcomb_f[4];
    __shared__ float sfc_tile[16 * 8];

    const f32x4 fzero = {0.f, 0.f, 0.f, 0.f};

    // ================= phase 1: rnn1 bottom-up =================
    // ---- weight fragments (f32 -> bf16, one-time) ----
    short8 wg1[4][5];
#pragma unroll
    for (int g = 0; g < 4; ++g) {
        const int gc = g * 64 + col;
#pragma unroll
        for (int kt = 0; kt < 5; ++kt) {
            short8 f;
#pragma unroll
            for (int j = 0; j < 8; ++j) {
                int k = kt * 32 + q * 8 + j;
                short v = 0;
                if (k < 64)       v = f2bf(Wx1[(k + 4) * 256 + gc]);
                else if (k < 68)  v = f2bf(Wx1[(k - 64) * 256 + gc]);
                else if (k >= 96) v = f2bf(Wh1[(k - 96) * 256 + gc]);
                f[j] = v;
            }
            wg1[g][kt] = f;
        }
    }
    short8 wl1[5];
#pragma unroll
    for (int kt = 0; kt < 5; ++kt) {
        short8 f;
#pragma unroll
        for (int j = 0; j < 8; ++j) {
            int k = kt * 32 + q * 8 + j;
            short v = 0;
            if (k < 64)       v = f2bf(Wxs1[(k + 4) * 64 + col]);
            else if (k < 68)  v = f2bf(Wxs1[(k - 64) * 64 + col]);
            else if (k >= 96) v = f2bf(Whs1[(k - 96) * 64 + col]);
            f[j] = v;
        }
        wl1[kt] = f;
    }

    // ---- surface-conditioned init (MFMA over padded K=32) ----
    float cst[4];
    {
        short8 aa, wih, wic;
#pragma unroll
        for (int j = 0; j < 8; ++j) {
            int k = q * 8 + j;
            aa[j]  = (k < 17) ? f2bf(aux[(size_t)(b0 + n) * 17 + k]) : (short)0;
            wih[j] = (k < 17) ? f2bf(Wsfc [k * 64 + col]) : (short)0;
            wic[j] = (k < 17) ? f2bf(Wsfc2[k * 64 + col]) : (short)0;
        }
        f32x4 ah = mfma16(aa, wih, fzero);
        f32x4 ac = mfma16(aa, wic, fzero);
        float bh = bsfc[col], bc = bsfc2[col];
        short* wr = r1 + 60 * 1152;
#pragma unroll
        for (int r = 0; r < 4; ++r) {
            wr[(4 * q + r) * 72 + col] = f2bf(tanhf_(ah[r] + bh));
            cst[r] = tanhf_(ac[r] + bc);
        }
    }
    __syncthreads();

    // ---- scan: step s processes level 59-s, eps1[s] ----
    for (int s = 0; s < 60; ++s) {
        const int lev = 59 - s;
        const short* hrow = r1 + (lev + 1) * 1152;
        short8 a3 = *(const short8*)&hrow[n * 72 + q * 8];
        short8 a4 = *(const short8*)&hrow[n * 72 + 32 + q * 8];

        const float* mrow = mem + (size_t)(b0 + n) * 3840 + lev * 64 + q * 8;
        float4 m0 = *(const float4*)mrow;
        float4 m1 = *(const float4*)(mrow + 4);
        float4 m2 = *(const float4*)(mrow + 32);
        float4 m3 = *(const float4*)(mrow + 36);
        short8 a0 = pack8(m0, m1);
        short8 a1 = pack8(m2, m3);
        short8 a2 = (short8)(short)0;
        if (q == 0) {
            float4 xv = *(const float4*)(xmain + (size_t)(b0 + n) * 240 + lev * 4);
            a2[0] = f2bf(xv.x); a2[1] = f2bf(xv.y);
            a2[2] = f2bf(xv.z); a2[3] = f2bf(xv.w);
        }
        short8 A[5] = {a0, a1, a2, a3, a4};

        const float* ep = eps1 + ((size_t)s << 18) + (size_t)(b0 + 4 * q) * 64 + col;
        float epsv[4];
#pragma unroll
        for (int r = 0; r < 4; ++r) epsv[r] = ep[r * 64];

        f32x4 acc[4];
        f32x4 accl = fzero;
#pragma unroll
        for (int g = 0; g < 4; ++g) {
            acc[g] = fzero;
#pragma unroll
            for (int kt = 0; kt < 5; ++kt) acc[g] = mfma16(A[kt], wg1[g][kt], acc[g]);
        }
#pragma unroll
        for (int kt = 0; kt < 5; ++kt) accl = mfma16(A[kt], wl1[kt], accl);

        short* wr2 = r1 + lev * 1152;
#pragma unroll
        for (int r = 0; r < 4; ++r) {
            float iv = sigmoidf_(acc[0][r]);
            float fv = sigmoidf_(acc[1][r]);
            float gv = tanhf_(acc[2][r]);
            float ov = sigmoidf_(acc[3][r]);
            float cn = fmaf(fv, cst[r], iv * gv);
            cst[r] = cn;
            float nz = epsv[r] * __expf(fminf(10.f, 0.5f * accl[r]));
            wr2[(4 * q + r) * 72 + col] = f2bf(fmaf(ov, tanhf_(cn), nz));
        }
        __syncthreads();   // writes to r1[lev] -> reads at step s+1
    }

    // ================= phase 2: rnn2 top-down + heads =================
    short8 wg2[4][4];
#pragma unroll
    for (int g = 0; g < 4; ++g) {
        const int gc = g * 64 + col;
#pragma unroll
        for (int kt = 0; kt < 4; ++kt) {
            short8 f;
#pragma unroll
            for (int j = 0; j < 8; ++j) {
                int k = kt * 32 + q * 8 + j;
                f[j] = (k < 64) ? f2bf(Wx2[k * 256 + gc]) : f2bf(Wh2[(k - 64) * 256 + gc]);
            }
            wg2[g][kt] = f;
        }
    }
    short8 wl2[4];
#pragma unroll
    for (int kt = 0; kt < 4; ++kt) {
        short8 f;
#pragma unroll
        for (int j = 0; j < 8; ++j) {
            int k = kt * 32 + q * 8 + j;
            f[j] = (k < 64) ? f2bf(Wxs2[k * 64 + col]) : f2bf(Whs2[(k - 64) * 64 + col]);
        }
        wl2[kt] = f;
    }
    short8 wlat_[2];
#pragma unroll
    for (int kt = 0; kt < 2; ++kt) {
        short8 f;
#pragma unroll
        for (int j = 0; j < 8; ++j) {
            int k = kt * 32 + q * 8 + j;
            f[j] = f2bf(Wlat[k * 64 + col]);
        }
        wlat_[kt] = f;
    }
    short8 whead[2];
#pragma unroll
    for (int kt = 0; kt < 2; ++kt) {
        short8 f;
#pragma unroll
        for (int j = 0; j < 8; ++j) {
            int k = kt * 32 + q * 8 + j;
            short v = 0;
            if (n < 2)       v = f2bf(Wmu[k * 2 + n]);
            else if (n < 4)  v = f2bf(Wlv[k * 2 + (n - 2)]);
            else if (n == 4) v = f2bf(Wsfco[k]);
            f[j] = v;
        }
        whead[kt] = f;
    }

    // ---- cooperative W_comb = W_lat @ W_out (64x4, f32) ----
    {
        int k = tid >> 2, y = tid & 3;
        float s = 0.f;
        for (int m = 0; m < 64; ++m) s += Wlat[k * 64 + m] * Wout[m * 4 + y];
        comb_f[tid] = s;
        if (tid < 4) {
            float s2 = 0.f;
            for (int m = 0; m < 64; ++m) s2 += blat[m] * Wout[m * 4 + tid];
            bcomb_f[tid] = s2 + bout[tid];
        }
    }

    // ---- TOA-conditioned init (K=2, pure VALU) ----
    float cst2[4];
    {
        float w0h = Wtoa[col],  w1h = Wtoa[64 + col],  bih = btoa[col];
        float w0c = Wtoa2[col], w1c = Wtoa2[64 + col], bic = btoa2[col];
        short* hw0 = hbuf;     // h2(init) -> buf 0
#pragma unroll
        for (int r = 0; r < 4; ++r) {
            int b = b0 + 4 * q + r;
            float t0 = aux[(size_t)b * 17 + 1];
            float t1 = aux[(size_t)b * 17 + 6];
            hw0[(4 * q + r) * 72 + col] = f2bf(tanhf_(fmaf(t0, w0h, fmaf(t1, w1h, bih))));
            cst2[r] = tanhf_(fmaf(t0, w0c, fmaf(t1, w1c, bic)));
        }
    }
    __syncthreads();

    short8 wcomb[2] = {(short8)(short)0, (short8)(short)0};
    float bcomb = 0.f;
    if (w == 0) {
#pragma unroll
        for (int kt = 0; kt < 2; ++kt) {
#pragma unroll
            for (int j = 0; j < 8; ++j) {
                int k = kt * 32 + q * 8 + j;
                wcomb[kt][j] = (n < 4) ? f2bf(comb_f[k * 4 + n]) : (short)0;
            }
        }
        if (n < 4) bcomb = bcomb_f[n];
    }
    const float bl = blat[col];

    // ---- scan: step s uses rnn1out[s] (r1[s]), eps2[s] ----
    for (int s = 0; s < 60; ++s) {
        const short* xr = r1 + s * 1152;
        short8 a0 = *(const short8*)&xr[n * 72 + q * 8];
        short8 a1 = *(const short8*)&xr[n * 72 + 32 + q * 8];
        const short* hc = hbuf + (s & 1) * 1152;
        short8 a2 = *(const short8*)&hc[n * 72 + q * 8];
        short8 a3 = *(const short8*)&hc[n * 72 + 32 + q * 8];
        short8 A[4] = {a0, a1, a2, a3};

        const float* ep = eps2 + ((size_t)s << 18) + (size_t)(b0 + 4 * q) * 64 + col;
        float epsv[4];
#pragma unroll
        for (int r = 0; r < 4; ++r) epsv[r] = ep[r * 64];

        f32x4 acc[4];
        f32x4 accl = fzero;
#pragma unroll
        for (int g = 0; g < 4; ++g) {
            acc[g] = fzero;
#pragma unroll
            for (int kt = 0; kt < 4; ++kt) acc[g] = mfma16(A[kt], wg2[g][kt], acc[g]);
        }
#pragma unroll
        for (int kt = 0; kt < 4; ++kt) accl = mfma16(A[kt], wl2[kt], accl);

        short* hw = hbuf + ((s + 1) & 1) * 1152;
#pragma unroll
        for (int r = 0; r < 4; ++r) {
            float iv = sigmoidf_(acc[0][r]);
            float fv = sigmoidf_(acc[1][r]);
            float gv = tanhf_(acc[2][r]);
            float ov = sigmoidf_(acc[3][r]);
            float cn = fmaf(fv, cst2[r], iv * gv);
            cst2[r] = cn;
            float nz = epsv[r] * __expf(fminf(10.f, 0.5f * accl[r]));
            hw[(4 * q + r) * 72 + col] = f2bf(fmaf(ov, tanhf_(cn), nz));
        }
        __syncthreads();   // h writes -> la reads + next-step reads

        // latent -> new_mem (f32); out via W_comb (wave 0, f32)
        short8 la0 = *(const short8*)&hw[n * 72 + q * 8];
        short8 la1 = *(const short8*)&hw[n * 72 + 32 + q * 8];
        f32x4 lat = mfma16(la0, wlat_[0], fzero);
        lat = mfma16(la1, wlat_[1], lat);
        float* mp = memp + (size_t)(b0 + 4 * q) * 3840 + s * 64 + col;
#pragma unroll
        for (int r = 0; r < 4; ++r) mp[r * 3840] = lat[r] + bl;

        if (w == 0) {
            f32x4 ot = mfma16(la0, wcomb[0], fzero);
            ot = mfma16(la1, wcomb[1], ot);
            if (n < 4) {
                float* op = outp + (size_t)(b0 + 4 * q) * 240 + s * 4 + n;
#pragma unroll
                for (int r = 0; r < 4; ++r) op[r * 240] = ot[r] + bcomb;
            }
        }
    }

    // ---- sfc heads from last hidden (hbuf slot 0 holds h2[59]) ----
    if (w == 1) {
        const short* hf = hbuf;   // (59+1)&1 == 0
        short8 la0 = *(const short8*)&hf[n * 72 + q * 8];
        short8 la1 = *(const short8*)&hf[n * 72 + 32 + q * 8];
        f32x4 hh = mfma16(la0, whead[0], fzero);
        hh = mfma16(la1, whead[1], hh);
        float bias = 0.f;
        if (n < 2)       bias = bmu[n];
        else if (n < 4)  bias = blv[n - 2];
        else if (n == 4) bias = bsfco[0];
        if (n < 5) {
#pragma unroll
            for (int r = 0; r < 4; ++r) sfc_tile[(4 * q + r) * 8 + n] = hh[r] + bias;
        }
    }
    __syncthreads();
    if (tid < 16) {
        int b = b0 + tid;
        float mu0 = sfc_tile[tid * 8 + 0], mu1 = sfc_tile[tid * 8 + 1];
        float lv0 = sfc_tile[tid * 8 + 2], lv1 = sfc_tile[tid * 8 + 3];
        float rad = sfc_tile[tid * 8 + 4];
        float e0 = epsS[(size_t)b * 2 + 0], e1 = epsS[(size_t)b * 2 + 1];
        sfcp[b * 3 + 0] = mu0 + e0 * __expf(fminf(20.f, 0.5f * lv0));
        sfcp[b * 3 + 1] = mu1 + e1 * __expf(fminf(20.f, 0.5f * lv1));
        sfcp[b * 3 + 2] = rad;
    }
}

extern "C" void kernel_launch(void* const* d_in, const int* in_sizes, int n_in,
                              void* d_out, int out_size, void* d_ws, size_t ws_size,
                              hipStream_t stream)
{
    const float* xmain = (const float*)d_in[0];
    const float* aux   = (const float*)d_in[1];
    const float* mem   = (const float*)d_in[2];
    const float* eps1  = (const float*)d_in[3];
    const float* eps2  = (const float*)d_in[4];
    const float* epsS  = (const float*)d_in[5];
    const float* Wsfc  = (const float*)d_in[6];
    const float* bsfc  = (const float*)d_in[7];
    const float* Wsfc2 = (const float*)d_in[8];
    const float* bsfc2 = (const float*)d_in[9];
    const float* Wtoa  = (const float*)d_in[10];
    const float* btoa  = (const float*)d_in[11];
    const float* Wtoa2 = (const float*)d_in[12];
    const float* btoa2 = (const float*)d_in[13];
    const float* Wx1   = (const float*)d_in[14];
    const float* Wh1   = (const float*)d_in[15];
    const float* Wxs1  = (const float*)d_in[16];
    const float* Whs1  = (const float*)d_in[17];
    const float* Wx2   = (const float*)d_in[18];
    const float* Wh2   = (const float*)d_in[19];
    const float* Wxs2  = (const float*)d_in[20];
    const float* Whs2  = (const float*)d_in[21];
    const float* Wlat  = (const float*)d_in[22];
    const float* blat  = (const float*)d_in[23];
    const float* Wout  = (const float*)d_in[24];
    const float* bout  = (const float*)d_in[25];
    const float* Wsfco = (const float*)d_in[26];
    const float* bsfco = (const float*)d_in[27];
    const float* Wmu   = (const float*)d_in[28];
    const float* bmu   = (const float*)d_in[29];
    const float* Wlv   = (const float*)d_in[30];
    const float* blv   = (const float*)d_in[31];

    float* outp = (float*)d_out;                       // (B,60,4) f32
    float* sfcp = outp + 4096 * 60 * 4;                // (B,3)
    float* memp = outp + 4096 * 60 * 4 + 4096 * 3;     // (B,60,64)

    k_fused<<<dim3(256), dim3(256), 0, stream>>>(
        xmain, aux, mem, eps1, eps2, epsS,
        Wsfc, bsfc, Wsfc2, bsfc2, Wtoa, btoa, Wtoa2, btoa2,
        Wx1, Wh1, Wxs1, Whs1, Wx2, Wh2, Wxs2, Whs2,
        Wlat, blat, Wout, bout, Wsfco, bsfco, Wmu, bmu, Wlv, blv,
        outp, sfcp, memp);
}

// Round 4
// 351.264 us; speedup vs baseline: 1.2186x; 1.2186x over previous
//
#include <hip/hip_runtime.h>
#include <hip/hip_bf16.h>

#define DEV __device__ __forceinline__

typedef __attribute__((ext_vector_type(8))) short short8;
typedef __attribute__((ext_vector_type(4))) float f32x4;
typedef __bf16 bf16x8 __attribute__((ext_vector_type(8)));

DEV f32x4 mfma16(short8 a, short8 b, f32x4 c) {
    return __builtin_amdgcn_mfma_f32_16x16x32_bf16(
        __builtin_bit_cast(bf16x8, a), __builtin_bit_cast(bf16x8, b), c, 0, 0, 0);
}

DEV short f2bf(float x) {
    unsigned int u = __float_as_uint(x);
    u += 0x7fffu + ((u >> 16) & 1u);   // RNE
    return (short)(u >> 16);
}
DEV float sigmoidf_(float x) {
    x = fminf(15.f, fmaxf(-15.f, x));
    float e = __expf(-x);
    return __builtin_amdgcn_rcpf(1.f + e);
}
DEV float tanhf_(float x) {
    x = fminf(15.f, fmaxf(-15.f, x));
    float e = __expf(-2.f * x);
    float r = __builtin_amdgcn_rcpf(1.f + e);
    return fmaf(-2.f * e, r, 1.f);
}
DEV short8 pack8(float4 lo, float4 hi) {
    short8 r;
    r[0] = f2bf(lo.x); r[1] = f2bf(lo.y); r[2] = f2bf(lo.z); r[3] = f2bf(lo.w);
    r[4] = f2bf(hi.x); r[5] = f2bf(hi.y); r[6] = f2bf(hi.z); r[7] = f2bf(hi.w);
    return r;
}

// ---------------------------------------------------------------------------
// Fully fused stochastic 2-layer LSTM. 256 WGs x 16 batch rows, 4 waves.
// Inputs f32, outputs f32. bf16 MFMA / f32 accumulate.
// rnn1out kept in LDS (61 level slots x 16 rows x 72-stride bf16).
// Round-4 change: register software-prefetch of all global loads (mem, xmain,
// eps1/eps2) one scan-step ahead, so HBM latency (~900cyc) overlaps compute
// instead of sitting on the serial critical path (1 wave/SIMD = no TLP hiding).
// ---------------------------------------------------------------------------
__global__ __launch_bounds__(256, 1)
void k_fused(const float* __restrict__ xmain, const float* __restrict__ aux,
             const float* __restrict__ mem,   const float* __restrict__ eps1,
             const float* __restrict__ eps2,  const float* __restrict__ epsS,
             const float* __restrict__ Wsfc,  const float* __restrict__ bsfc,
             const float* __restrict__ Wsfc2, const float* __restrict__ bsfc2,
             const float* __restrict__ Wtoa,  const float* __restrict__ btoa,
             const float* __restrict__ Wtoa2, const float* __restrict__ btoa2,
             const float* __restrict__ Wx1,   const float* __restrict__ Wh1,
             const float* __restrict__ Wxs1,  const float* __restrict__ Whs1,
             const float* __restrict__ Wx2,   const float* __restrict__ Wh2,
             const float* __restrict__ Wxs2,  const float* __restrict__ Whs2,
             const float* __restrict__ Wlat,  const float* __restrict__ blat,
             const float* __restrict__ Wout,  const float* __restrict__ bout,
             const float* __restrict__ Wsfco, const float* __restrict__ bsfco,
             const float* __restrict__ Wmu,   const float* __restrict__ bmu,
             const float* __restrict__ Wlv,   const float* __restrict__ blv,
             float* __restrict__ outp, float* __restrict__ sfcp, float* __restrict__ memp)
{
    const int tid  = threadIdx.x;
    const int w    = tid >> 6;
    const int lane = tid & 63;
    const int q    = lane >> 4;
    const int n    = lane & 15;
    const int b0   = blockIdx.x << 4;
    const int col  = w * 16 + n;          // hidden column owned by this lane

    // LDS: 61 level slots (slot 60 = h0) of 16 rows x 72-stride bf16.
    __shared__ __align__(16) short r1[61 * 1152];      // 140544 B
    __shared__ __align__(16) short hbuf[2 * 1152];     //   4608 B
    __shared__ float comb_f[64 * 4];
    __shared__ float bcomb_f[4];
    __shared__ float sfc_tile[16 * 8];

    const f32x4 fzero = {0.f, 0.f, 0.f, 0.f};

    // ================= phase 1: rnn1 bottom-up =================
    // ---- weight fragments (f32 -> bf16, one-time) ----
    short8 wg1[4][5];
#pragma unroll
    for (int g = 0; g < 4; ++g) {
        const int gc = g * 64 + col;
#pragma unroll
        for (int kt = 0; kt < 5; ++kt) {
            short8 f;
#pragma unroll
            for (int j = 0; j < 8; ++j) {
                int k = kt * 32 + q * 8 + j;
                short v = 0;
                if (k < 64)       v = f2bf(Wx1[(k + 4) * 256 + gc]);
                else if (k < 68)  v = f2bf(Wx1[(k - 64) * 256 + gc]);
                else if (k >= 96) v = f2bf(Wh1[(k - 96) * 256 + gc]);
                f[j] = v;
            }
            wg1[g][kt] = f;
        }
    }
    short8 wl1[5];
#pragma unroll
    for (int kt = 0; kt < 5; ++kt) {
        short8 f;
#pragma unroll
        for (int j = 0; j < 8; ++j) {
            int k = kt * 32 + q * 8 + j;
            short v = 0;
            if (k < 64)       v = f2bf(Wxs1[(k + 4) * 64 + col]);
            else if (k < 68)  v = f2bf(Wxs1[(k - 64) * 64 + col]);
            else if (k >= 96) v = f2bf(Whs1[(k - 96) * 64 + col]);
            f[j] = v;
        }
        wl1[kt] = f;
    }

    // ---- surface-conditioned init (MFMA over padded K=32) ----
    float cst[4];
    {
        short8 aa, wih, wic;
#pragma unroll
        for (int j = 0; j < 8; ++j) {
            int k = q * 8 + j;
            aa[j]  = (k < 17) ? f2bf(aux[(size_t)(b0 + n) * 17 + k]) : (short)0;
            wih[j] = (k < 17) ? f2bf(Wsfc [k * 64 + col]) : (short)0;
            wic[j] = (k < 17) ? f2bf(Wsfc2[k * 64 + col]) : (short)0;
        }
        f32x4 ah = mfma16(aa, wih, fzero);
        f32x4 ac = mfma16(aa, wic, fzero);
        float bh = bsfc[col], bc = bsfc2[col];
        short* wr = r1 + 60 * 1152;
#pragma unroll
        for (int r = 0; r < 4; ++r) {
            wr[(4 * q + r) * 72 + col] = f2bf(tanhf_(ah[r] + bh));
            cst[r] = tanhf_(ac[r] + bc);
        }
    }

    // ---- prefetch step 0 (lev 59) ----
    const float* mbase = mem + (size_t)(b0 + n) * 3840;
    const float* xbase = xmain + (size_t)(b0 + n) * 240;
    float4 pm0, pm1, pm2, pm3, pxv;
    float pep[4];
    {
        const float* mrow = mbase + 59 * 64 + q * 8;
        pm0 = *(const float4*)mrow;
        pm1 = *(const float4*)(mrow + 4);
        pm2 = *(const float4*)(mrow + 32);
        pm3 = *(const float4*)(mrow + 36);
        pxv = *(const float4*)(xbase + 59 * 4);
        const float* ep = eps1 + (size_t)(b0 + 4 * q) * 64 + col;
#pragma unroll
        for (int r = 0; r < 4; ++r) pep[r] = ep[r * 64];
    }
    __syncthreads();

    // ---- scan: step s processes level 59-s, eps1[s] ----
    for (int s = 0; s < 60; ++s) {
        const int lev = 59 - s;

        // current step's data (from prefetch regs)
        float4 m0 = pm0, m1 = pm1, m2 = pm2, m3 = pm3, xv = pxv;
        float epsv[4] = {pep[0], pep[1], pep[2], pep[3]};

        // issue next step's loads NOW (overlap with MFMA+elementwise below)
        if (s < 59) {
            const float* mrow = mbase + (lev - 1) * 64 + q * 8;
            pm0 = *(const float4*)mrow;
            pm1 = *(const float4*)(mrow + 4);
            pm2 = *(const float4*)(mrow + 32);
            pm3 = *(const float4*)(mrow + 36);
            pxv = *(const float4*)(xbase + (lev - 1) * 4);
            const float* ep = eps1 + ((size_t)(s + 1) << 18) + (size_t)(b0 + 4 * q) * 64 + col;
#pragma unroll
            for (int r = 0; r < 4; ++r) pep[r] = ep[r * 64];
        }

        const short* hrow = r1 + (lev + 1) * 1152;
        short8 a3 = *(const short8*)&hrow[n * 72 + q * 8];
        short8 a4 = *(const short8*)&hrow[n * 72 + 32 + q * 8];

        short8 a0 = pack8(m0, m1);
        short8 a1 = pack8(m2, m3);
        short8 a2 = (short8)(short)0;
        if (q == 0) {
            a2[0] = f2bf(xv.x); a2[1] = f2bf(xv.y);
            a2[2] = f2bf(xv.z); a2[3] = f2bf(xv.w);
        }
        short8 A[5] = {a0, a1, a2, a3, a4};

        f32x4 acc[4];
        f32x4 accl = fzero;
#pragma unroll
        for (int g = 0; g < 4; ++g) {
            acc[g] = fzero;
#pragma unroll
            for (int kt = 0; kt < 5; ++kt) acc[g] = mfma16(A[kt], wg1[g][kt], acc[g]);
        }
#pragma unroll
        for (int kt = 0; kt < 5; ++kt) accl = mfma16(A[kt], wl1[kt], accl);

        short* wr2 = r1 + lev * 1152;
#pragma unroll
        for (int r = 0; r < 4; ++r) {
            float iv = sigmoidf_(acc[0][r]);
            float fv = sigmoidf_(acc[1][r]);
            float gv = tanhf_(acc[2][r]);
            float ov = sigmoidf_(acc[3][r]);
            float cn = fmaf(fv, cst[r], iv * gv);
            cst[r] = cn;
            float nz = epsv[r] * __expf(fminf(10.f, 0.5f * accl[r]));
            wr2[(4 * q + r) * 72 + col] = f2bf(fmaf(ov, tanhf_(cn), nz));
        }
        __syncthreads();   // writes to r1[lev] -> reads at step s+1
    }

    // ================= phase 2: rnn2 top-down + heads =================
    short8 wg2[4][4];
#pragma unroll
    for (int g = 0; g < 4; ++g) {
        const int gc = g * 64 + col;
#pragma unroll
        for (int kt = 0; kt < 4; ++kt) {
            short8 f;
#pragma unroll
            for (int j = 0; j < 8; ++j) {
                int k = kt * 32 + q * 8 + j;
                f[j] = (k < 64) ? f2bf(Wx2[k * 256 + gc]) : f2bf(Wh2[(k - 64) * 256 + gc]);
            }
            wg2[g][kt] = f;
        }
    }
    short8 wl2[4];
#pragma unroll
    for (int kt = 0; kt < 4; ++kt) {
        short8 f;
#pragma unroll
        for (int j = 0; j < 8; ++j) {
            int k = kt * 32 + q * 8 + j;
            f[j] = (k < 64) ? f2bf(Wxs2[k * 64 + col]) : f2bf(Whs2[(k - 64) * 64 + col]);
        }
        wl2[kt] = f;
    }
    short8 wlat_[2];
#pragma unroll
    for (int kt = 0; kt < 2; ++kt) {
        short8 f;
#pragma unroll
        for (int j = 0; j < 8; ++j) {
            int k = kt * 32 + q * 8 + j;
            f[j] = f2bf(Wlat[k * 64 + col]);
        }
        wlat_[kt] = f;
    }
    short8 whead[2];
#pragma unroll
    for (int kt = 0; kt < 2; ++kt) {
        short8 f;
#pragma unroll
        for (int j = 0; j < 8; ++j) {
            int k = kt * 32 + q * 8 + j;
            short v = 0;
            if (n < 2)       v = f2bf(Wmu[k * 2 + n]);
            else if (n < 4)  v = f2bf(Wlv[k * 2 + (n - 2)]);
            else if (n == 4) v = f2bf(Wsfco[k]);
            f[j] = v;
        }
        whead[kt] = f;
    }

    // ---- cooperative W_comb = W_lat @ W_out (64x4, f32) ----
    {
        int k = tid >> 2, y = tid & 3;
        float s = 0.f;
        for (int m = 0; m < 64; ++m) s += Wlat[k * 64 + m] * Wout[m * 4 + y];
        comb_f[tid] = s;
        if (tid < 4) {
            float s2 = 0.f;
            for (int m = 0; m < 64; ++m) s2 += blat[m] * Wout[m * 4 + tid];
            bcomb_f[tid] = s2 + bout[tid];
        }
    }

    // ---- TOA-conditioned init (K=2, pure VALU) ----
    float cst2[4];
    {
        float w0h = Wtoa[col],  w1h = Wtoa[64 + col],  bih = btoa[col];
        float w0c = Wtoa2[col], w1c = Wtoa2[64 + col], bic = btoa2[col];
        short* hw0 = hbuf;     // h2(init) -> buf 0
#pragma unroll
        for (int r = 0; r < 4; ++r) {
            int b = b0 + 4 * q + r;
            float t0 = aux[(size_t)b * 17 + 1];
            float t1 = aux[(size_t)b * 17 + 6];
            hw0[(4 * q + r) * 72 + col] = f2bf(tanhf_(fmaf(t0, w0h, fmaf(t1, w1h, bih))));
            cst2[r] = tanhf_(fmaf(t0, w0c, fmaf(t1, w1c, bic)));
        }
    }
    __syncthreads();

    short8 wcomb[2] = {(short8)(short)0, (short8)(short)0};
    float bcomb = 0.f;
    if (w == 0) {
#pragma unroll
        for (int kt = 0; kt < 2; ++kt) {
#pragma unroll
            for (int j = 0; j < 8; ++j) {
                int k = kt * 32 + q * 8 + j;
                wcomb[kt][j] = (n < 4) ? f2bf(comb_f[k * 4 + n]) : (short)0;
            }
        }
        if (n < 4) bcomb = bcomb_f[n];
    }
    const float bl = blat[col];

    // ---- prefetch eps2 step 0 ----
    float pep2[4];
    {
        const float* ep = eps2 + (size_t)(b0 + 4 * q) * 64 + col;
#pragma unroll
        for (int r = 0; r < 4; ++r) pep2[r] = ep[r * 64];
    }

    // ---- scan: step s uses rnn1out[s] (r1[s]), eps2[s] ----
    for (int s = 0; s < 60; ++s) {
        float epsv[4] = {pep2[0], pep2[1], pep2[2], pep2[3]};
        if (s < 59) {
            const float* ep = eps2 + ((size_t)(s + 1) << 18) + (size_t)(b0 + 4 * q) * 64 + col;
#pragma unroll
            for (int r = 0; r < 4; ++r) pep2[r] = ep[r * 64];
        }

        const short* xr = r1 + s * 1152;
        short8 a0 = *(const short8*)&xr[n * 72 + q * 8];
        short8 a1 = *(const short8*)&xr[n * 72 + 32 + q * 8];
        const short* hc = hbuf + (s & 1) * 1152;
        short8 a2 = *(const short8*)&hc[n * 72 + q * 8];
        short8 a3 = *(const short8*)&hc[n * 72 + 32 + q * 8];
        short8 A[4] = {a0, a1, a2, a3};

        f32x4 acc[4];
        f32x4 accl = fzero;
#pragma unroll
        for (int g = 0; g < 4; ++g) {
            acc[g] = fzero;
#pragma unroll
            for (int kt = 0; kt < 4; ++kt) acc[g] = mfma16(A[kt], wg2[g][kt], acc[g]);
        }
#pragma unroll
        for (int kt = 0; kt < 4; ++kt) accl = mfma16(A[kt], wl2[kt], accl);

        short* hw = hbuf + ((s + 1) & 1) * 1152;
#pragma unroll
        for (int r = 0; r < 4; ++r) {
            float iv = sigmoidf_(acc[0][r]);
            float fv = sigmoidf_(acc[1][r]);
            float gv = tanhf_(acc[2][r]);
            float ov = sigmoidf_(acc[3][r]);
            float cn = fmaf(fv, cst2[r], iv * gv);
            cst2[r] = cn;
            float nz = epsv[r] * __expf(fminf(10.f, 0.5f * accl[r]));
            hw[(4 * q + r) * 72 + col] = f2bf(fmaf(ov, tanhf_(cn), nz));
        }
        __syncthreads();   // h writes -> la reads + next-step reads

        // latent -> new_mem (f32); out via W_comb (wave 0, f32)
        short8 la0 = *(const short8*)&hw[n * 72 + q * 8];
        short8 la1 = *(const short8*)&hw[n * 72 + 32 + q * 8];
        f32x4 lat = mfma16(la0, wlat_[0], fzero);
        lat = mfma16(la1, wlat_[1], lat);
        float* mp = memp + (size_t)(b0 + 4 * q) * 3840 + s * 64 + col;
#pragma unroll
        for (int r = 0; r < 4; ++r) mp[r * 3840] = lat[r] + bl;

        if (w == 0) {
            f32x4 ot = mfma16(la0, wcomb[0], fzero);
            ot = mfma16(la1, wcomb[1], ot);
            if (n < 4) {
                float* op = outp + (size_t)(b0 + 4 * q) * 240 + s * 4 + n;
#pragma unroll
                for (int r = 0; r < 4; ++r) op[r * 240] = ot[r] + bcomb;
            }
        }
    }

    // ---- sfc heads from last hidden (hbuf slot 0 holds h2[59]) ----
    if (w == 1) {
        const short* hf = hbuf;   // (59+1)&1 == 0
        short8 la0 = *(const short8*)&hf[n * 72 + q * 8];
        short8 la1 = *(const short8*)&hf[n * 72 + 32 + q * 8];
        f32x4 hh = mfma16(la0, whead[0], fzero);
        hh = mfma16(la1, whead[1], hh);
        float bias = 0.f;
        if (n < 2)       bias = bmu[n];
        else if (n < 4)  bias = blv[n - 2];
        else if (n == 4) bias = bsfco[0];
        if (n < 5) {
#pragma unroll
            for (int r = 0; r < 4; ++r) sfc_tile[(4 * q + r) * 8 + n] = hh[r] + bias;
        }
    }
    __syncthreads();
    if (tid < 16) {
        int b = b0 + tid;
        float mu0 = sfc_tile[tid * 8 + 0], mu1 = sfc_tile[tid * 8 + 1];
        float lv0 = sfc_tile[tid * 8 + 2], lv1 = sfc_tile[tid * 8 + 3];
        float rad = sfc_tile[tid * 8 + 4];
        float e0 = epsS[(size_t)b * 2 + 0], e1 = epsS[(size_t)b * 2 + 1];
        sfcp[b * 3 + 0] = mu0 + e0 * __expf(fminf(20.f, 0.5f * lv0));
        sfcp[b * 3 + 1] = mu1 + e1 * __expf(fminf(20.f, 0.5f * lv1));
        sfcp[b * 3 + 2] = rad;
    }
}

extern "C" void kernel_launch(void* const* d_in, const int* in_sizes, int n_in,
                              void* d_out, int out_size, void* d_ws, size_t ws_size,
                              hipStream_t stream)
{
    const float* xmain = (const float*)d_in[0];
    const float* aux   = (const float*)d_in[1];
    const float* mem   = (const float*)d_in[2];
    const float* eps1  = (const float*)d_in[3];
    const float* eps2  = (const float*)d_in[4];
    const float* epsS  = (const float*)d_in[5];
    const float* Wsfc  = (const float*)d_in[6];
    const float* bsfc  = (const float*)d_in[7];
    const float* Wsfc2 = (const float*)d_in[8];
    const float* bsfc2 = (const float*)d_in[9];
    const float* Wtoa  = (const float*)d_in[10];
    const float* btoa  = (const float*)d_in[11];
    const float* Wtoa2 = (const float*)d_in[12];
    const float* btoa2 = (const float*)d_in[13];
    const float* Wx1   = (const float*)d_in[14];
    const float* Wh1   = (const float*)d_in[15];
    const float* Wxs1  = (const float*)d_in[16];
    const float* Whs1  = (const float*)d_in[17];
    const float* Wx2   = (const float*)d_in[18];
    const float* Wh2   = (const float*)d_in[19];
    const float* Wxs2  = (const float*)d_in[20];
    const float* Whs2  = (const float*)d_in[21];
    const float* Wlat  = (const float*)d_in[22];
    const float* blat  = (const float*)d_in[23];
    const float* Wout  = (const float*)d_in[24];
    const float* bout  = (const float*)d_in[25];
    const float* Wsfco = (const float*)d_in[26];
    const float* bsfco = (const float*)d_in[27];
    const float* Wmu   = (const float*)d_in[28];
    const float* bmu   = (const float*)d_in[29];
    const float* Wlv   = (const float*)d_in[30];
    const float* blv   = (const float*)d_in[31];

    float* outp = (float*)d_out;                       // (B,60,4) f32
    float* sfcp = outp + 4096 * 60 * 4;                // (B,3)
    float* memp = outp + 4096 * 60 * 4 + 4096 * 3;     // (B,60,64)

    k_fused<<<dim3(256), dim3(256), 0, stream>>>(
        xmain, aux, mem, eps1, eps2, epsS,
        Wsfc, bsfc, Wsfc2, bsfc2, Wtoa, btoa, Wtoa2, btoa2,
        Wx1, Wh1, Wxs1, Whs1, Wx2, Wh2, Wxs2, Whs2,
        Wlat, blat, Wout, bout, Wsfco, bsfco, Wmu, bmu, Wlv, blv,
        outp, sfcp, memp);
}